// Round 3
// baseline (265.823 us; speedup 1.0000x reference)
//
#include <hip/hip_runtime.h>

// 3-level db4 (Daubechies-2) 2D DWT with periodization, coefficient tiling.
// Input x: (8,16,512,512) fp32 -> out: (8,16,512,512) fp32.
// Cascade: level kernel reads NxN LL, writes 3 detail subbands into final
// d_out tile positions and LL into d_ws (or d_out top-left for last level).
// ws usage: LL1 (128*256*256 f32 = 32 MiB) + LL2 (8 MiB) = 40 MiB.

constexpr int TI = 16;               // output rows per block
constexpr int TJ = 32;               // output cols per block
constexpr int ROWS = 2 * TI + 2;     // 34 staged input rows
constexpr int COLS = 2 * TJ + 2;     // 66 staged input cols
constexpr int LDS_STRIDE = COLS + 2; // 68

__global__ __launch_bounds__(256)
void dwt_level(const float* __restrict__ src, int N,
               float* __restrict__ out,
               float* __restrict__ ll, int ll_rs, size_t ll_cs)
{
    const int S = N >> 1;
    const int mask = N - 1;          // N is a power of two -> cheap periodization
    __shared__ float tile[ROWS][LDS_STRIDE];

    const int tx = threadIdx.x;      // 0..31
    const int ty = threadIdx.y;      // 0..7
    const int tid = ty * 32 + tx;
    const int j0 = blockIdx.x * TJ;
    const int i0 = blockIdx.y * TI;
    const int ch = blockIdx.z;

    const float* s = src + (size_t)ch * N * N;
    const int gr0 = 2 * i0 - 1;      // circular pad: left=1
    const int gc0 = 2 * j0 - 1;

    // Stage 34x66 input patch (coalesced along columns; wrap only at edges).
    for (int k = tid; k < ROWS * COLS; k += 256) {
        const int r = k / COLS;
        const int c = k - r * COLS;
        const int gr = (gr0 + r) & mask;
        const int gc = (gc0 + c) & mask;
        tile[r][c] = s[(size_t)gr * N + gc];
    }
    __syncthreads();

    // db4 decomposition taps (cross-correlation order, matches torch conv1d)
    const float h0[4] = { 0.4829629131445341f,  0.8365163037378079f,
                          0.2241438680420134f, -0.1294095225512604f };
    const float h1[4] = { -0.1294095225512604f, -0.2241438680420134f,
                           0.8365163037378079f, -0.4829629131445341f };

    float* outc = out + (size_t)ch * (512 * 512);
    float* llc  = ll  + (size_t)ch * ll_cs;

    #pragma unroll
    for (int rr = 0; rr < 2; ++rr) {
        const int i = ty + rr * 8;   // local output row 0..15
        const int j = tx;            // local output col 0..31
        float a_ll = 0.f, a_lh = 0.f, a_hl = 0.f, a_hh = 0.f;
        #pragma unroll
        for (int p = 0; p < 4; ++p) {
            const float v0 = tile[2 * i + p][2 * j + 0];
            const float v1 = tile[2 * i + p][2 * j + 1];
            const float v2 = tile[2 * i + p][2 * j + 2];
            const float v3 = tile[2 * i + p][2 * j + 3];
            const float lo = h0[0] * v0 + h0[1] * v1 + h0[2] * v2 + h0[3] * v3;
            const float hi = h1[0] * v0 + h1[1] * v1 + h1[2] * v2 + h1[3] * v3;
            a_ll += h0[p] * lo;      // h0 on W then h0 on H
            a_lh += h1[p] * lo;      // h0 on W, h1 on H -> top-right tile
            a_hl += h0[p] * hi;      // h1 on W, h0 on H -> bottom-left tile
            a_hh += h1[p] * hi;      // bottom-right tile
        }
        const int gi = i0 + i;
        const int gj = j0 + j;
        llc[(size_t)gi * ll_rs + gj]            = a_ll;
        outc[(size_t)gi * 512 + (S + gj)]       = a_lh;
        outc[(size_t)(S + gi) * 512 + gj]       = a_hl;
        outc[(size_t)(S + gi) * 512 + (S + gj)] = a_hh;
    }
}

extern "C" void kernel_launch(void* const* d_in, const int* in_sizes, int n_in,
                              void* d_out, int out_size, void* d_ws, size_t ws_size,
                              hipStream_t stream) {
    const float* x = (const float*)d_in[0];
    float* out = (float*)d_out;
    const int C = in_sizes[0] / (512 * 512);   // 8*16 = 128 channels

    float* ll1 = (float*)d_ws;                         // C * 256*256
    float* ll2 = ll1 + (size_t)C * 256 * 256;          // C * 128*128

    dim3 blk(32, 8);
    // level 0: 512 -> details at S=256 tiles, LL1 -> ws
    dwt_level<<<dim3(256 / TJ, 256 / TI, C), blk, 0, stream>>>(
        x, 512, out, ll1, 256, (size_t)256 * 256);
    // level 1: 256 -> details at S=128 tiles, LL2 -> ws
    dwt_level<<<dim3(128 / TJ, 128 / TI, C), blk, 0, stream>>>(
        ll1, 256, out, ll2, 128, (size_t)128 * 128);
    // level 2: 128 -> details at S=64 tiles, LL3 -> out[0:64,0:64]
    dwt_level<<<dim3(64 / TJ, 64 / TI, C), blk, 0, stream>>>(
        ll2, 128, out, out, 512, (size_t)512 * 512);
}

// Round 4
// 251.480 us; speedup vs baseline: 1.0570x; 1.0570x over previous
//
#include <hip/hip_runtime.h>

// 3-level db4 2D DWT, periodization, coefficient tiling. fp32 (8,16,512,512).
// v2: staging via aligned float4 loads batched into registers (3/thread) before
// LDS writes -> restores memory-level parallelism (v1 had VGPR=12, ~1
// outstanding scalar load/wave, 3.1 TB/s).

constexpr int TI = 16;               // output rows per block
constexpr int TJ = 32;               // output cols per block
constexpr int ROWS = 2 * TI + 2;     // 34 staged input rows
constexpr int CVEC = 18;             // float4 per staged row (72 floats)
constexpr int LDSW = CVEC * 4;       // 72 floats/row, 288 B (16B-aligned)
constexpr int NV4  = ROWS * CVEC;    // 612 float4 per block
constexpr int VPT  = (NV4 + 255) / 256;  // 3 float4 per thread

__global__ __launch_bounds__(256)
void dwt_level(const float* __restrict__ src, int N,
               float* __restrict__ out,
               float* __restrict__ ll, int ll_rs, size_t ll_cs)
{
    const int S = N >> 1;
    const int mask = N - 1;
    __shared__ float tile[ROWS * LDSW];

    const int tx = threadIdx.x;      // 0..31
    const int ty = threadIdx.y;      // 0..7
    const int tid = ty * 32 + tx;
    const int j0 = blockIdx.x * TJ;
    const int i0 = blockIdx.y * TI;
    const int ch = blockIdx.z;

    const float* s = src + (size_t)ch * N * N;
    const int gr0 = 2 * i0 - 1;      // circular pad: left=1
    const int cb0 = 2 * j0 - 4;      // aligned staging base (covers col 2*j0-1-.. halo)

    // Batched staging: issue all loads into registers, then write LDS.
    float4 v[VPT];
    int lofs[VPT];
    #pragma unroll
    for (int k = 0; k < VPT; ++k) {
        int idx = tid + k * 256;
        if (idx > NV4 - 1) idx = NV4 - 1;          // clamp: duplicate store, benign
        const int r = idx / CVEC;
        const int m = idx - r * CVEC;
        const int gr = (gr0 + r) & mask;
        const int gc = (cb0 + 4 * m) & mask;       // 16B-aligned, never straddles wrap
        v[k] = *reinterpret_cast<const float4*>(s + (size_t)gr * N + gc);
        lofs[k] = r * LDSW + 4 * m;
    }
    #pragma unroll
    for (int k = 0; k < VPT; ++k)
        *reinterpret_cast<float4*>(&tile[lofs[k]]) = v[k];
    __syncthreads();

    // db4 decomposition taps (cross-correlation order, matches torch conv1d)
    const float h0[4] = { 0.4829629131445341f,  0.8365163037378079f,
                          0.2241438680420134f, -0.1294095225512604f };
    const float h1[4] = { -0.1294095225512604f, -0.2241438680420134f,
                           0.8365163037378079f, -0.4829629131445341f };

    float* outc = out + (size_t)ch * (512 * 512);
    float* llc  = ll  + (size_t)ch * ll_cs;

    #pragma unroll
    for (int rr = 0; rr < 2; ++rr) {
        const int i = ty + rr * 8;   // local output row 0..15
        const int j = tx;            // local output col 0..31
        // global col 2*(j0+j)-1+q lives at tile col (2*j+3+q)
        const int base = 2 * j + 3;
        float a_ll = 0.f, a_lh = 0.f, a_hl = 0.f, a_hh = 0.f;
        #pragma unroll
        for (int p = 0; p < 4; ++p) {
            const float* row = &tile[(2 * i + p) * LDSW];
            const float v0 = row[base + 0];
            const float v1 = row[base + 1];
            const float v2 = row[base + 2];
            const float v3 = row[base + 3];
            const float lo = h0[0] * v0 + h0[1] * v1 + h0[2] * v2 + h0[3] * v3;
            const float hi = h1[0] * v0 + h1[1] * v1 + h1[2] * v2 + h1[3] * v3;
            a_ll += h0[p] * lo;
            a_lh += h1[p] * lo;      // h0 on W, h1 on H -> top-right tile
            a_hl += h0[p] * hi;      // h1 on W, h0 on H -> bottom-left tile
            a_hh += h1[p] * hi;      // bottom-right tile
        }
        const int gi = i0 + i;
        const int gj = j0 + j;
        llc[(size_t)gi * ll_rs + gj]            = a_ll;
        outc[(size_t)gi * 512 + (S + gj)]       = a_lh;
        outc[(size_t)(S + gi) * 512 + gj]       = a_hl;
        outc[(size_t)(S + gi) * 512 + (S + gj)] = a_hh;
    }
}

extern "C" void kernel_launch(void* const* d_in, const int* in_sizes, int n_in,
                              void* d_out, int out_size, void* d_ws, size_t ws_size,
                              hipStream_t stream) {
    const float* x = (const float*)d_in[0];
    float* out = (float*)d_out;
    const int C = in_sizes[0] / (512 * 512);   // 8*16 = 128 channels

    float* ll1 = (float*)d_ws;                         // C * 256*256
    float* ll2 = ll1 + (size_t)C * 256 * 256;          // C * 128*128

    dim3 blk(32, 8);
    // level 0: 512 -> details at S=256 tiles, LL1 -> ws
    dwt_level<<<dim3(256 / TJ, 256 / TI, C), blk, 0, stream>>>(
        x, 512, out, ll1, 256, (size_t)256 * 256);
    // level 1: 256 -> details at S=128 tiles, LL2 -> ws
    dwt_level<<<dim3(128 / TJ, 128 / TI, C), blk, 0, stream>>>(
        ll1, 256, out, ll2, 128, (size_t)128 * 128);
    // level 2: 128 -> details at S=64 tiles, LL3 -> out[0:64,0:64]
    dwt_level<<<dim3(64 / TJ, 64 / TI, C), blk, 0, stream>>>(
        ll2, 128, out, out, 512, (size_t)512 * 512);
}

// Round 5
// 243.008 us; speedup vs baseline: 1.0939x; 1.0349x over previous
//
#include <hip/hip_runtime.h>

// Fully-fused 3-level db4 2D DWT, periodization, coefficient tiling.
// fp32 (8,16,512,512) -> (8,16,512,512). ONE kernel: each block owns an 8x16
// LL3 tile (=> 64x128 input region + halos), recomputes LL1/LL2 halos locally
// in LDS, writes every subband to its final d_out position. No d_ws use.
// Traffic: 128 MiB read (x1.37 halo, L2-absorbed) + 128 MiB write.

constexpr int IN_R = 78;             // input rows staged  (2*(2*(2*8+2)+2)+2)
constexpr int IN_CV = 36;            // float4 per staged row
constexpr int IN_C = IN_CV * 4;      // 144 floats (need 142)
constexpr int L1_R = 38, L1_C = 70, L1_S = 72;
constexpr int L2_R = 18, L2_C = 34, L2_S = 36;

__global__ __launch_bounds__(256)
void dwt_fused(const float* __restrict__ x, float* __restrict__ out)
{
    __shared__ float IN[IN_R * IN_C];    // 44,928 B
    __shared__ float L1[L1_R * L1_S];    // 10,944 B
    __shared__ float L2[L2_R * L2_S];    //  2,592 B   (total 58.5 KB -> 2 blk/CU)

    const int tid = threadIdx.x;         // 0..255
    const int cb  = blockIdx.x;          // 0..3   (LL3 col tile)
    const int b   = blockIdx.y;          // 0..7   (LL3 row tile)
    const int ch  = blockIdx.z;          // 0..127

    const float* s = x   + (size_t)ch * (512 * 512);
    float*       o = out + (size_t)ch * (512 * 512);

    const int r0 = 64 * b - 7;           // staged input row base (circular)
    const int c0 = 128 * cb - 8;         // staged input col base (16B aligned)

    // ---- stage 78x144 input patch: 2808 float4, 11/thread, batched ----
    float4 v[11]; int lof[11];
    #pragma unroll
    for (int k = 0; k < 11; ++k) {
        int idx = tid + 256 * k;
        if (idx > IN_R * IN_CV - 1) idx = IN_R * IN_CV - 1;   // dup-write, benign
        const int r = idx / IN_CV, m = idx - r * IN_CV;
        const int gr = (r0 + r) & 511;
        const int gc = (c0 + 4 * m) & 511;
        v[k] = *reinterpret_cast<const float4*>(s + (size_t)gr * 512 + gc);
        lof[k] = r * IN_C + 4 * m;
    }
    #pragma unroll
    for (int k = 0; k < 11; ++k)
        *reinterpret_cast<float4*>(&IN[lof[k]]) = v[k];
    __syncthreads();

    const float h0[4] = { 0.4829629131445341f,  0.8365163037378079f,
                          0.2241438680420134f, -0.1294095225512604f };
    const float h1[4] = { -0.1294095225512604f, -0.2241438680420134f,
                           0.8365163037378079f, -0.4829629131445341f };

    // ---- LL1 38x70 (global rows 32b-3.., cols 64cb-3..) ----
    #pragma unroll
    for (int k = 0; k < 11; ++k) {
        int idx = tid + 256 * k;
        if (idx > L1_R * L1_C - 1) idx = L1_R * L1_C - 1;
        const int r = idx / L1_C, m = idx - r * L1_C;
        float a = 0.f;
        #pragma unroll
        for (int p = 0; p < 4; ++p) {
            const float* row = &IN[(2 * r + p) * IN_C + 2 * m + 1];
            a += h0[p] * (h0[0]*row[0] + h0[1]*row[1] + h0[2]*row[2] + h0[3]*row[3]);
        }
        L1[r * L1_S + m] = a;
    }

    // ---- L0 details 32x64 (owned), reads IN only ----
    #pragma unroll
    for (int k = 0; k < 8; ++k) {
        const int idx = tid + 256 * k;
        const int i = idx >> 6, j = idx & 63;
        float lh = 0.f, hl = 0.f, hh = 0.f;
        #pragma unroll
        for (int p = 0; p < 4; ++p) {
            const float* row = &IN[(2 * i + 6 + p) * IN_C + 2 * j + 7];
            const float v0 = row[0], v1 = row[1], v2 = row[2], v3 = row[3];
            const float lo = h0[0]*v0 + h0[1]*v1 + h0[2]*v2 + h0[3]*v3;
            const float hi = h1[0]*v0 + h1[1]*v1 + h1[2]*v2 + h1[3]*v3;
            lh += h1[p] * lo; hl += h0[p] * hi; hh += h1[p] * hi;
        }
        const int gi = 32 * b + i, gj = 64 * cb + j;
        o[(size_t)gi * 512 + (256 + gj)]         = lh;
        o[(size_t)(256 + gi) * 512 + gj]         = hl;
        o[(size_t)(256 + gi) * 512 + (256 + gj)] = hh;
    }
    __syncthreads();

    // ---- LL2 18x34 (global rows 16b-1.., cols 32cb-1..) ----
    #pragma unroll
    for (int k = 0; k < 3; ++k) {
        int idx = tid + 256 * k;
        if (idx > L2_R * L2_C - 1) idx = L2_R * L2_C - 1;
        const int r = idx / L2_C, m = idx - r * L2_C;
        float a = 0.f;
        #pragma unroll
        for (int p = 0; p < 4; ++p) {
            const float* row = &L1[(2 * r + p) * L1_S + 2 * m];
            a += h0[p] * (h0[0]*row[0] + h0[1]*row[1] + h0[2]*row[2] + h0[3]*row[3]);
        }
        L2[r * L2_S + m] = a;
    }

    // ---- L1 details 16x32 (owned), reads L1 ----
    #pragma unroll
    for (int k = 0; k < 2; ++k) {
        const int idx = tid + 256 * k;
        const int i = idx >> 5, j = idx & 31;
        float lh = 0.f, hl = 0.f, hh = 0.f;
        #pragma unroll
        for (int p = 0; p < 4; ++p) {
            const float* row = &L1[(2 * i + 2 + p) * L1_S + 2 * j + 2];
            const float v0 = row[0], v1 = row[1], v2 = row[2], v3 = row[3];
            const float lo = h0[0]*v0 + h0[1]*v1 + h0[2]*v2 + h0[3]*v3;
            const float hi = h1[0]*v0 + h1[1]*v1 + h1[2]*v2 + h1[3]*v3;
            lh += h1[p] * lo; hl += h0[p] * hi; hh += h1[p] * hi;
        }
        const int gi = 16 * b + i, gj = 32 * cb + j;
        o[(size_t)gi * 512 + (128 + gj)]         = lh;
        o[(size_t)(128 + gi) * 512 + gj]         = hl;
        o[(size_t)(128 + gi) * 512 + (128 + gj)] = hh;
    }
    __syncthreads();

    // ---- L2 quads 8x16 (owned) + LL3, reads L2 ----
    if (tid < 128) {
        const int i = tid >> 4, j = tid & 15;
        float ll = 0.f, lh = 0.f, hl = 0.f, hh = 0.f;
        #pragma unroll
        for (int p = 0; p < 4; ++p) {
            const float* row = &L2[(2 * i + p) * L2_S + 2 * j];
            const float v0 = row[0], v1 = row[1], v2 = row[2], v3 = row[3];
            const float lo = h0[0]*v0 + h0[1]*v1 + h0[2]*v2 + h0[3]*v3;
            const float hi = h1[0]*v0 + h1[1]*v1 + h1[2]*v2 + h1[3]*v3;
            ll += h0[p] * lo; lh += h1[p] * lo; hl += h0[p] * hi; hh += h1[p] * hi;
        }
        const int gi = 8 * b + i, gj = 16 * cb + j;
        o[(size_t)gi * 512 + gj]               = ll;
        o[(size_t)gi * 512 + (64 + gj)]        = lh;
        o[(size_t)(64 + gi) * 512 + gj]        = hl;
        o[(size_t)(64 + gi) * 512 + (64 + gj)] = hh;
    }
}

extern "C" void kernel_launch(void* const* d_in, const int* in_sizes, int n_in,
                              void* d_out, int out_size, void* d_ws, size_t ws_size,
                              hipStream_t stream) {
    const float* x = (const float*)d_in[0];
    float* out = (float*)d_out;
    const int C = in_sizes[0] / (512 * 512);   // 128 channels
    dwt_fused<<<dim3(4, 8, C), dim3(256), 0, stream>>>(x, out);
}